// Round 6
// baseline (207.148 us; speedup 1.0000x reference)
//
#include <hip/hip_runtime.h>

#define NHEAD 12
#define DHEAD 64
#define SEQ   2048
#define NB    2
#define NX    768
#define MTOK  (NB * SEQ)   // 4096

typedef __attribute__((ext_vector_type(8))) short short8;
typedef __attribute__((ext_vector_type(4))) short short4v;
typedef __attribute__((ext_vector_type(4))) float f32x4;

__device__ __forceinline__ unsigned short f2bf(float x) {
    union { float f; unsigned u; } v; v.f = x;
    unsigned r = v.u + 0x7fffu + ((v.u >> 16) & 1u);
    return (unsigned short)(r >> 16);
}

#define MFMA32(a, b, c) __builtin_amdgcn_mfma_f32_16x16x32_bf16(a, b, c, 0, 0, 0)
#define MFMA16(a, b, c) __builtin_amdgcn_mfma_f32_16x16x16bf16_1k(a, b, c, 0, 0, 0)

// ---------------------------------------------------------------------------
// fp32 -> bf16 elementwise (float4 loads, ushort4 stores)
// ---------------------------------------------------------------------------
__global__ __launch_bounds__(256)
void cvt_k(const float* __restrict__ X, unsigned short* __restrict__ Y, int n4)
{
    int i = blockIdx.x * 256 + threadIdx.x;
    if (i >= n4) return;
    float4 v = ((const float4*)X)[i];
    ushort4 o;
    o.x = f2bf(v.x); o.y = f2bf(v.y); o.z = f2bf(v.z); o.w = f2bf(v.w);
    ((ushort4*)Y)[i] = o;
}

// ---------------------------------------------------------------------------
// W[K][N] fp32 -> T[N][K] bf16 (transpose via 32x32 LDS tile)
// ---------------------------------------------------------------------------
__global__ __launch_bounds__(256)
void cvtT_k(const float* __restrict__ W, unsigned short* __restrict__ T, int K, int N)
{
    __shared__ float tile[32][33];
    const int t = threadIdx.x;
    const int r = t >> 5, c = t & 31;
    const int k0 = blockIdx.y * 32, n0 = blockIdx.x * 32;
#pragma unroll
    for (int i = 0; i < 4; i++)
        tile[r + i * 8][c] = W[(size_t)(k0 + r + i * 8) * N + n0 + c];
    __syncthreads();
#pragma unroll
    for (int i = 0; i < 4; i++) {
        int n = r + i * 8;
        T[(size_t)(n0 + n) * K + k0 + c] = f2bf(tile[c][n]);
    }
}

// ---------------------------------------------------------------------------
// bf16 MFMA GEMM (unchanged from R5): C[M,N] = A[M,K] @ Bt[N,K]^T + bias.
// MODE 0: QKV epilogue (q,k [B,H,S,D] bf16; q scaled 0.125*log2e for exp2;
// v -> [B,H,D,S]). MODE 1: fp32 out + bias.
// ---------------------------------------------------------------------------
template<int MODE>
__global__ __launch_bounds__(256, 3)
void gemm_bf(const unsigned short* __restrict__ A,   // [M][K] bf16
             const unsigned short* __restrict__ Bt,  // [N][K] bf16
             const float* __restrict__ bias,
             float* __restrict__ fo,
             unsigned short* __restrict__ qb, unsigned short* __restrict__ kb2,
             unsigned short* __restrict__ vtb,
             int M, int N, int K)
{
    __shared__ __align__(16) unsigned char sm[2][16384];  // [buf][A 8KB | B 8KB]
    const int t = threadIdx.x;
    const int w = t >> 6, lane = t & 63;
    const int lo16 = lane & 15, quad = lane >> 4;
    const int ib = blockIdx.y * 128, jb = blockIdx.x * 128;

    f32x4 acc[4][4];
#pragma unroll
    for (int mt = 0; mt < 4; mt++)
#pragma unroll
        for (int nt = 0; nt < 4; nt++) acc[mt][nt] = (f32x4){0.f, 0.f, 0.f, 0.f};

    const int srow = lane >> 2;   // 0..15 within seg
    const int sj   = lane & 3;

    auto stage = [&](int buf, int k0) {
#pragma unroll
        for (int i = 0; i < 4; i++) {
            const int u   = i * 4 + w;
            const int p   = u >> 3;
            const int row = (u & 7) * 16 + srow;
            const int sc  = sj ^ (row & 3);
            const unsigned short* g = (p == 0)
                ? (A  + (size_t)(ib + row) * K + k0 + sc * 8)
                : (Bt + (size_t)(jb + row) * K + k0 + sc * 8);
            void* lp = &sm[buf][p * 8192 + (u & 7) * 1024];
            __builtin_amdgcn_global_load_lds(
                (const __attribute__((address_space(1))) unsigned int*)g,
                (__attribute__((address_space(3))) unsigned int*)lp, 16, 0, 0);
        }
    };

    const int mrow = (w >> 1) * 64;
    const int nrow = (w & 1) * 64;

    stage(0, 0);
    const int NIT = K / 32;
    for (int kt = 0; kt < NIT; kt++) {
        const int buf = kt & 1;
        __syncthreads();
        if (kt + 1 < NIT) stage(buf ^ 1, (kt + 1) * 32);

        short8 af[4], bf[4];
#pragma unroll
        for (int mt = 0; mt < 4; mt++) {
            const int row = mrow + mt * 16 + lo16;
            af[mt] = *(const short8*)&sm[buf][row * 64 + ((quad ^ (row & 3)) * 16)];
        }
#pragma unroll
        for (int nt = 0; nt < 4; nt++) {
            const int row = nrow + nt * 16 + lo16;
            bf[nt] = *(const short8*)&sm[buf][8192 + row * 64 + ((quad ^ (row & 3)) * 16)];
        }
#pragma unroll
        for (int mt = 0; mt < 4; mt++)
#pragma unroll
            for (int nt = 0; nt < 4; nt++)
                acc[mt][nt] = MFMA32(af[mt], bf[nt], acc[mt][nt]);
    }

    if constexpr (MODE == 0) {
        const int which = jb / NX;   // 0=q 1=k 2=v, uniform per block
#pragma unroll
        for (int nt = 0; nt < 4; nt++) {
            const int j  = jb + nrow + nt * 16 + lo16;
            const int cc = j - which * NX;
            const int hh = cc >> 6, dd = cc & 63;
            const float bj = bias[j];
#pragma unroll
            for (int mt = 0; mt < 4; mt++) {
                const int m0 = ib + mrow + mt * 16 + quad * 4;
                const int bb = m0 >> 11;
                const int s0 = m0 & 2047;
                const size_t hb = (size_t)(bb * NHEAD + hh);
                if (which == 2) {
                    ushort4 pv;
                    pv.x = f2bf(acc[mt][nt][0] + bj);
                    pv.y = f2bf(acc[mt][nt][1] + bj);
                    pv.z = f2bf(acc[mt][nt][2] + bj);
                    pv.w = f2bf(acc[mt][nt][3] + bj);
                    *(ushort4*)(vtb + (hb * DHEAD + dd) * SEQ + s0) = pv;
                } else {
                    unsigned short* dst = (which == 0) ? qb : kb2;
                    // q: fold 1/sqrt(64) AND log2(e) (attn uses exp2)
                    const float sc = (which == 0) ? 0.1803368801f : 1.0f;
#pragma unroll
                    for (int r = 0; r < 4; r++)
                        dst[(hb * SEQ + s0 + r) * DHEAD + dd] =
                            f2bf((acc[mt][nt][r] + bj) * sc);
                }
            }
        }
    } else {
#pragma unroll
        for (int nt = 0; nt < 4; nt++) {
            const int j  = jb + nrow + nt * 16 + lo16;
            const float bj = bias[j];
#pragma unroll
            for (int mt = 0; mt < 4; mt++) {
                const int m0 = ib + mrow + mt * 16 + quad * 4;
#pragma unroll
                for (int r = 0; r < 4; r++)
                    fo[(size_t)(m0 + r) * N + j] = acc[mt][nt][r] + bj;
            }
        }
    }
}

// ---------------------------------------------------------------------------
// Flash attention v4: key-split waves, ZERO LDS in main loop.
// Block = 4 waves, 64 queries (all shared); wave w owns keys w*16..+15 of
// each 64-key tile -> K/V fragments are wave-private, loaded DIRECTLY from
// global to registers (K: dwordx4, V: dwordx2), prefetched 1 iter ahead.
// No-max softmax via exp2 (scale pre-folded); P stays in registers (S^T
// C-layout == x16 B-fragment layout). Cross-wave O/l combine once via LDS.
// ---------------------------------------------------------------------------
__global__ __launch_bounds__(256, 3)
void attn_bf(const unsigned short* __restrict__ qb, const unsigned short* __restrict__ kb,
             const unsigned short* __restrict__ vtb, unsigned short* __restrict__ ab)
{
    __shared__ float red[12544];  // partials [w][slot3][q64][dim16] + lsums[4][64]

    const int t = threadIdx.x;
    const int w = t >> 6, lane = t & 63;
    const int lo16 = lane & 15, quad = lane >> 4;

    // XCD-swizzled decode: same bh stays on one XCD (K/V L2 locality)
    const int id = blockIdx.x;            // 768
    const int xcd = id & 7, slot = id >> 3;
    const int bh = xcd * 3 + slot % 3;
    const int q0 = (slot / 3) * 64;
    const int b = bh / NHEAD, h = bh % NHEAD;

    const unsigned short* Qb = qb  + (size_t)bh * SEQ * DHEAD;
    const unsigned short* Kb = kb  + (size_t)bh * SEQ * DHEAD;
    const unsigned short* Vb = vtb + (size_t)bh * DHEAD * SEQ;

    // Q^T B-fragments for all 4 q-subtiles (held in registers)
    short8 qf[4][2];
#pragma unroll
    for (int qt = 0; qt < 4; qt++) {
        const unsigned short* qp = Qb + (size_t)(q0 + qt * 16 + lo16) * DHEAD + quad * 8;
        qf[qt][0] = *(const short8*)qp;
        qf[qt][1] = *(const short8*)(qp + 32);
    }

    f32x4 oacc[4][4];   // [d-tile][q-tile] partial O^T (this wave's keys only)
#pragma unroll
    for (int dt = 0; dt < 4; dt++)
#pragma unroll
        for (int qt = 0; qt < 4; qt++) oacc[dt][qt] = (f32x4){0.f, 0.f, 0.f, 0.f};
    float lsum[4] = {0.f, 0.f, 0.f, 0.f};

    // wave-private fragment pointers
    const unsigned short* kp = Kb + (size_t)(w * 16 + lo16) * DHEAD + quad * 8;   // A-frag: key=lo16
    const unsigned short* vp = Vb + (size_t)lo16 * SEQ + w * 16 + quad * 4;       // A-frag: dim=lo16

    short8 kc0 = *(const short8*)kp;
    short8 kc1 = *(const short8*)(kp + 32);
    short4v vc[4];
#pragma unroll
    for (int dt = 0; dt < 4; dt++) vc[dt] = *(const short4v*)(vp + (size_t)dt * 16 * SEQ);

    const unsigned sel = 0x07060302u;

    for (int kt = 0; kt < SEQ / 64; kt++) {
        // ---- prefetch next tile's fragments (clamped on last iter) ----
        const int ktn = (kt < SEQ / 64 - 1) ? kt + 1 : kt;
        const unsigned short* kpn = kp + (size_t)ktn * 64 * DHEAD;
        const unsigned short* vpn = vp + (size_t)ktn * 64;
        short8 kn0 = *(const short8*)kpn;
        short8 kn1 = *(const short8*)(kpn + 32);
        short4v vn[4];
#pragma unroll
        for (int dt = 0; dt < 4; dt++) vn[dt] = *(const short4v*)(vpn + (size_t)dt * 16 * SEQ);

        // ---- S^T = K @ Q^T over this wave's 16 keys (keys in C-rows) ----
        f32x4 s[4];
#pragma unroll
        for (int qt = 0; qt < 4; qt++) {
            f32x4 a = (f32x4){0.f, 0.f, 0.f, 0.f};
            a = MFMA32(kc0, qf[qt][0], a);
            a = MFMA32(kc1, qf[qt][1], a);
            s[qt] = a;
        }

        // ---- p = exp2(s) (scale pre-folded); pack P via v_perm ----
        short4v pf[4];
#pragma unroll
        for (int qt = 0; qt < 4; qt++) {
            union { float f; unsigned u; } p0, p1, p2, p3;
            p0.f = __builtin_amdgcn_exp2f(s[qt][0]);
            p1.f = __builtin_amdgcn_exp2f(s[qt][1]);
            p2.f = __builtin_amdgcn_exp2f(s[qt][2]);
            p3.f = __builtin_amdgcn_exp2f(s[qt][3]);
            lsum[qt] += (p0.f + p1.f) + (p2.f + p3.f);
            union { unsigned u[2]; short4v v; } pk;
            pk.u[0] = __builtin_amdgcn_perm(p1.u, p0.u, sel);
            pk.u[1] = __builtin_amdgcn_perm(p3.u, p2.u, sel);
            pf[qt] = pk.v;
        }

        // ---- O^T += V^T @ P^T (K=16 = this wave's keys) ----
#pragma unroll
        for (int dt = 0; dt < 4; dt++)
#pragma unroll
            for (int qt = 0; qt < 4; qt++)
                oacc[dt][qt] = MFMA16(vc[dt], pf[qt], oacc[dt][qt]);

        kc0 = kn0; kc1 = kn1;
#pragma unroll
        for (int dt = 0; dt < 4; dt++) vc[dt] = vn[dt];
    }

    // ---- per-wave l reduction across quads (disjoint keys) ----
#pragma unroll
    for (int qt = 0; qt < 4; qt++) {
        lsum[qt] += __shfl_xor(lsum[qt], 16);
        lsum[qt] += __shfl_xor(lsum[qt], 32);
    }
    if (quad == 0) {
#pragma unroll
        for (int qt = 0; qt < 4; qt++)
            red[12288 + w * 64 + qt * 16 + lo16] = lsum[qt];
    }

    // ---- write partial O^T for dt != w (layout [q][dim16] -> b128, 2-way max)
#pragma unroll
    for (int dt = 0; dt < 4; dt++) {
        if (dt == w) continue;
        const int sl = dt - (dt > w ? 1 : 0);
#pragma unroll
        for (int qt = 0; qt < 4; qt++)
            *(f32x4*)&red[((w * 3 + sl) * 64 + qt * 16 + lo16) * 16 + quad * 4] = oacc[dt][qt];
    }
    __syncthreads();

    // ---- wave w owns dim-tile w: add the other 3 waves' partials ----
#pragma unroll
    for (int ow = 0; ow < 4; ow++) {
        if (ow == w) continue;
        const int sl = w - (w > ow ? 1 : 0);
#pragma unroll
        for (int qt = 0; qt < 4; qt++)
            oacc[w][qt] += *(const f32x4*)&red[((ow * 3 + sl) * 64 + qt * 16 + lo16) * 16 + quad * 4];
    }

    // ---- normalize, pack bf16, store ----
#pragma unroll
    for (int qt = 0; qt < 4; qt++) {
        const int q = qt * 16 + lo16;
        const float lt = red[12288 + q] + red[12288 + 64 + q]
                       + red[12288 + 128 + q] + red[12288 + 192 + q];
        const float inv = 1.0f / lt;
        f32x4 o = oacc[w][qt] * inv;
        union { float f; unsigned u; } a0, a1, a2, a3;
        a0.f = o[0]; a1.f = o[1]; a2.f = o[2]; a3.f = o[3];
        uint2 pk;
        pk.x = __builtin_amdgcn_perm(a1.u, a0.u, sel);
        pk.y = __builtin_amdgcn_perm(a3.u, a2.u, sel);
        *(uint2*)(ab + (size_t)(b * SEQ + q0 + q) * NX + h * DHEAD + w * 16 + quad * 4) = pk;
    }
}

// ---------------------------------------------------------------------------
extern "C" void kernel_launch(void* const* d_in, const int* in_sizes, int n_in,
                              void* d_out, int out_size, void* d_ws, size_t ws_size,
                              hipStream_t stream)
{
    const float* hs     = (const float*)d_in[0];
    const float* w_attn = (const float*)d_in[1];
    const float* b_attn = (const float*)d_in[2];
    const float* w_proj = (const float*)d_in[3];
    const float* b_proj = (const float*)d_in[4];
    float* out = (float*)d_out;

    unsigned short* wsu = (unsigned short*)d_ws;
    unsigned short* Abf  = wsu;                      // 4096*768
    unsigned short* WtA  = Abf  + 3145728;           // 2304*768
    unsigned short* WtP  = WtA  + 1769472;           // 768*768
    unsigned short* qbuf = WtP  + 589824;            // [B,H,S,D]
    unsigned short* kbuf = qbuf + 3145728;           // [B,H,S,D]
    unsigned short* vtbf = kbuf + 3145728;           // [B,H,D,S]
    unsigned short* abf  = vtbf + 3145728;           // [B,S,NX] bf16

    // converts
    cvt_k<<<3072, 256, 0, stream>>>(hs, Abf, 786432);
    cvtT_k<<<dim3(72, 24), 256, 0, stream>>>(w_attn, WtA, NX, 3 * NX);
    cvtT_k<<<dim3(24, 24), 256, 0, stream>>>(w_proj, WtP, NX, NX);

    // QKV GEMM
    gemm_bf<0><<<dim3(18, 32), 256, 0, stream>>>(
        Abf, WtA, b_attn, nullptr, qbuf, kbuf, vtbf, MTOK, 3 * NX, NX);

    // attention
    attn_bf<<<768, 256, 0, stream>>>(qbuf, kbuf, vtbf, abf);

    // output projection
    gemm_bf<1><<<dim3(6, 32), 256, 0, stream>>>(
        abf, WtP, b_proj, out, nullptr, nullptr, nullptr, MTOK, NX, NX);
}

// Round 7
// 195.097 us; speedup vs baseline: 1.0618x; 1.0618x over previous
//
#include <hip/hip_runtime.h>

#define NHEAD 12
#define DHEAD 64
#define SEQ   2048
#define NB    2
#define NX    768
#define MTOK  (NB * SEQ)   // 4096

typedef __attribute__((ext_vector_type(8))) short short8;
typedef __attribute__((ext_vector_type(4))) short short4v;
typedef __attribute__((ext_vector_type(4))) float f32x4;

__device__ __forceinline__ unsigned short f2bf(float x) {
    union { float f; unsigned u; } v; v.f = x;
    unsigned r = v.u + 0x7fffu + ((v.u >> 16) & 1u);
    return (unsigned short)(r >> 16);
}

#define MFMA32(a, b, c) __builtin_amdgcn_mfma_f32_16x16x32_bf16(a, b, c, 0, 0, 0)
#define MFMA16(a, b, c) __builtin_amdgcn_mfma_f32_16x16x16bf16_1k(a, b, c, 0, 0, 0)

// ---------------------------------------------------------------------------
// fp32 -> bf16 elementwise (float4 loads, ushort4 stores)
// ---------------------------------------------------------------------------
__global__ __launch_bounds__(256)
void cvt_k(const float* __restrict__ X, unsigned short* __restrict__ Y, int n4)
{
    int i = blockIdx.x * 256 + threadIdx.x;
    if (i >= n4) return;
    float4 v = ((const float4*)X)[i];
    ushort4 o;
    o.x = f2bf(v.x); o.y = f2bf(v.y); o.z = f2bf(v.z); o.w = f2bf(v.w);
    ((ushort4*)Y)[i] = o;
}

// ---------------------------------------------------------------------------
// W[K][N] fp32 -> T[N][K] bf16 (transpose via 32x32 LDS tile)
// ---------------------------------------------------------------------------
__global__ __launch_bounds__(256)
void cvtT_k(const float* __restrict__ W, unsigned short* __restrict__ T, int K, int N)
{
    __shared__ float tile[32][33];
    const int t = threadIdx.x;
    const int r = t >> 5, c = t & 31;
    const int k0 = blockIdx.y * 32, n0 = blockIdx.x * 32;
#pragma unroll
    for (int i = 0; i < 4; i++)
        tile[r + i * 8][c] = W[(size_t)(k0 + r + i * 8) * N + n0 + c];
    __syncthreads();
#pragma unroll
    for (int i = 0; i < 4; i++) {
        int n = r + i * 8;
        T[(size_t)(n0 + n) * K + k0 + c] = f2bf(tile[c][n]);
    }
}

// ---------------------------------------------------------------------------
// bf16 MFMA GEMM (unchanged from R5): C[M,N] = A[M,K] @ Bt[N,K]^T + bias.
// MODE 0: QKV epilogue (q,k [B,H,S,D] bf16; q scaled 0.125*log2e for exp2;
// v -> [B,H,D,S]). MODE 1: fp32 out + bias.
// ---------------------------------------------------------------------------
template<int MODE>
__global__ __launch_bounds__(256, 3)
void gemm_bf(const unsigned short* __restrict__ A,   // [M][K] bf16
             const unsigned short* __restrict__ Bt,  // [N][K] bf16
             const float* __restrict__ bias,
             float* __restrict__ fo,
             unsigned short* __restrict__ qb, unsigned short* __restrict__ kb2,
             unsigned short* __restrict__ vtb,
             int M, int N, int K)
{
    __shared__ __align__(16) unsigned char sm[2][16384];  // [buf][A 8KB | B 8KB]
    const int t = threadIdx.x;
    const int w = t >> 6, lane = t & 63;
    const int lo16 = lane & 15, quad = lane >> 4;
    const int ib = blockIdx.y * 128, jb = blockIdx.x * 128;

    f32x4 acc[4][4];
#pragma unroll
    for (int mt = 0; mt < 4; mt++)
#pragma unroll
        for (int nt = 0; nt < 4; nt++) acc[mt][nt] = (f32x4){0.f, 0.f, 0.f, 0.f};

    const int srow = lane >> 2;   // 0..15 within seg
    const int sj   = lane & 3;

    auto stage = [&](int buf, int k0) {
#pragma unroll
        for (int i = 0; i < 4; i++) {
            const int u   = i * 4 + w;
            const int p   = u >> 3;
            const int row = (u & 7) * 16 + srow;
            const int sc  = sj ^ (row & 3);
            const unsigned short* g = (p == 0)
                ? (A  + (size_t)(ib + row) * K + k0 + sc * 8)
                : (Bt + (size_t)(jb + row) * K + k0 + sc * 8);
            void* lp = &sm[buf][p * 8192 + (u & 7) * 1024];
            __builtin_amdgcn_global_load_lds(
                (const __attribute__((address_space(1))) unsigned int*)g,
                (__attribute__((address_space(3))) unsigned int*)lp, 16, 0, 0);
        }
    };

    const int mrow = (w >> 1) * 64;
    const int nrow = (w & 1) * 64;

    stage(0, 0);
    const int NIT = K / 32;
    for (int kt = 0; kt < NIT; kt++) {
        const int buf = kt & 1;
        __syncthreads();
        if (kt + 1 < NIT) stage(buf ^ 1, (kt + 1) * 32);

        short8 af[4], bf[4];
#pragma unroll
        for (int mt = 0; mt < 4; mt++) {
            const int row = mrow + mt * 16 + lo16;
            af[mt] = *(const short8*)&sm[buf][row * 64 + ((quad ^ (row & 3)) * 16)];
        }
#pragma unroll
        for (int nt = 0; nt < 4; nt++) {
            const int row = nrow + nt * 16 + lo16;
            bf[nt] = *(const short8*)&sm[buf][8192 + row * 64 + ((quad ^ (row & 3)) * 16)];
        }
#pragma unroll
        for (int mt = 0; mt < 4; mt++)
#pragma unroll
            for (int nt = 0; nt < 4; nt++)
                acc[mt][nt] = MFMA32(af[mt], bf[nt], acc[mt][nt]);
    }

    if constexpr (MODE == 0) {
        const int which = jb / NX;   // 0=q 1=k 2=v, uniform per block
#pragma unroll
        for (int nt = 0; nt < 4; nt++) {
            const int j  = jb + nrow + nt * 16 + lo16;
            const int cc = j - which * NX;
            const int hh = cc >> 6, dd = cc & 63;
            const float bj = bias[j];
#pragma unroll
            for (int mt = 0; mt < 4; mt++) {
                const int m0 = ib + mrow + mt * 16 + quad * 4;
                const int bb = m0 >> 11;
                const int s0 = m0 & 2047;
                const size_t hb = (size_t)(bb * NHEAD + hh);
                if (which == 2) {
                    ushort4 pv;
                    pv.x = f2bf(acc[mt][nt][0] + bj);
                    pv.y = f2bf(acc[mt][nt][1] + bj);
                    pv.z = f2bf(acc[mt][nt][2] + bj);
                    pv.w = f2bf(acc[mt][nt][3] + bj);
                    *(ushort4*)(vtb + (hb * DHEAD + dd) * SEQ + s0) = pv;
                } else {
                    unsigned short* dst = (which == 0) ? qb : kb2;
                    // q: fold 1/sqrt(64) AND log2(e) (attn uses exp2)
                    const float sc = (which == 0) ? 0.1803368801f : 1.0f;
#pragma unroll
                    for (int r = 0; r < 4; r++)
                        dst[(hb * SEQ + s0 + r) * DHEAD + dd] =
                            f2bf((acc[mt][nt][r] + bj) * sc);
                }
            }
        }
    } else {
#pragma unroll
        for (int nt = 0; nt < 4; nt++) {
            const int j  = jb + nrow + nt * 16 + lo16;
            const float bj = bias[j];
#pragma unroll
            for (int mt = 0; mt < 4; mt++) {
                const int m0 = ib + mrow + mt * 16 + quad * 4;
#pragma unroll
                for (int r = 0; r < 4; r++)
                    fo[(size_t)(m0 + r) * N + j] = acc[mt][nt][r] + bj;
            }
        }
    }
}

// ---------------------------------------------------------------------------
// Flash attention v4.1: key-split waves, ZERO LDS in main loop.
// Identical to R6 except the cross-wave combine extracts the wave's own
// dim-tile via a wave-uniform STATIC branch ladder — no dynamic indexing
// into register arrays (R6's oacc[w] forced the accumulator into scratch:
// WRITE_SIZE 6 MB -> 105 MB, the whole regression).
// ---------------------------------------------------------------------------
__global__ __launch_bounds__(256, 3)
void attn_bf(const unsigned short* __restrict__ qb, const unsigned short* __restrict__ kb,
             const unsigned short* __restrict__ vtb, unsigned short* __restrict__ ab)
{
    __shared__ float red[12544];  // partials [w][slot3][q64][dim16] + lsums[4][64]

    const int t = threadIdx.x;
    const int w = t >> 6, lane = t & 63;
    const int lo16 = lane & 15, quad = lane >> 4;

    // XCD-swizzled decode: same bh stays on one XCD (K/V L2 locality)
    const int id = blockIdx.x;            // 768
    const int xcd = id & 7, slot = id >> 3;
    const int bh = xcd * 3 + slot % 3;
    const int q0 = (slot / 3) * 64;
    const int b = bh / NHEAD, h = bh % NHEAD;

    const unsigned short* Qb = qb  + (size_t)bh * SEQ * DHEAD;
    const unsigned short* Kb = kb  + (size_t)bh * SEQ * DHEAD;
    const unsigned short* Vb = vtb + (size_t)bh * DHEAD * SEQ;

    // Q^T B-fragments for all 4 q-subtiles (held in registers)
    short8 qf[4][2];
#pragma unroll
    for (int qt = 0; qt < 4; qt++) {
        const unsigned short* qp = Qb + (size_t)(q0 + qt * 16 + lo16) * DHEAD + quad * 8;
        qf[qt][0] = *(const short8*)qp;
        qf[qt][1] = *(const short8*)(qp + 32);
    }

    f32x4 oacc[4][4];   // [d-tile][q-tile] partial O^T (this wave's keys only)
#pragma unroll
    for (int dt = 0; dt < 4; dt++)
#pragma unroll
        for (int qt = 0; qt < 4; qt++) oacc[dt][qt] = (f32x4){0.f, 0.f, 0.f, 0.f};
    float lsum[4] = {0.f, 0.f, 0.f, 0.f};

    // wave-private fragment pointers
    const unsigned short* kp = Kb + (size_t)(w * 16 + lo16) * DHEAD + quad * 8;   // A-frag: key=lo16
    const unsigned short* vp = Vb + (size_t)lo16 * SEQ + w * 16 + quad * 4;       // A-frag: dim=lo16

    short8 kc0 = *(const short8*)kp;
    short8 kc1 = *(const short8*)(kp + 32);
    short4v vc[4];
#pragma unroll
    for (int dt = 0; dt < 4; dt++) vc[dt] = *(const short4v*)(vp + (size_t)dt * 16 * SEQ);

    const unsigned sel = 0x07060302u;

    for (int kt = 0; kt < SEQ / 64; kt++) {
        // ---- prefetch next tile's fragments (clamped on last iter) ----
        const int ktn = (kt < SEQ / 64 - 1) ? kt + 1 : kt;
        const unsigned short* kpn = kp + (size_t)ktn * 64 * DHEAD;
        const unsigned short* vpn = vp + (size_t)ktn * 64;
        short8 kn0 = *(const short8*)kpn;
        short8 kn1 = *(const short8*)(kpn + 32);
        short4v vn[4];
#pragma unroll
        for (int dt = 0; dt < 4; dt++) vn[dt] = *(const short4v*)(vpn + (size_t)dt * 16 * SEQ);

        // ---- S^T = K @ Q^T over this wave's 16 keys (keys in C-rows) ----
        f32x4 s[4];
#pragma unroll
        for (int qt = 0; qt < 4; qt++) {
            f32x4 a = (f32x4){0.f, 0.f, 0.f, 0.f};
            a = MFMA32(kc0, qf[qt][0], a);
            a = MFMA32(kc1, qf[qt][1], a);
            s[qt] = a;
        }

        // ---- p = exp2(s) (scale pre-folded); pack P via v_perm ----
        short4v pf[4];
#pragma unroll
        for (int qt = 0; qt < 4; qt++) {
            union { float f; unsigned u; } p0, p1, p2, p3;
            p0.f = __builtin_amdgcn_exp2f(s[qt][0]);
            p1.f = __builtin_amdgcn_exp2f(s[qt][1]);
            p2.f = __builtin_amdgcn_exp2f(s[qt][2]);
            p3.f = __builtin_amdgcn_exp2f(s[qt][3]);
            lsum[qt] += (p0.f + p1.f) + (p2.f + p3.f);
            union { unsigned u[2]; short4v v; } pk;
            pk.u[0] = __builtin_amdgcn_perm(p1.u, p0.u, sel);
            pk.u[1] = __builtin_amdgcn_perm(p3.u, p2.u, sel);
            pf[qt] = pk.v;
        }

        // ---- O^T += V^T @ P^T (K=16 = this wave's keys) ----
#pragma unroll
        for (int dt = 0; dt < 4; dt++)
#pragma unroll
            for (int qt = 0; qt < 4; qt++)
                oacc[dt][qt] = MFMA16(vc[dt], pf[qt], oacc[dt][qt]);

        kc0 = kn0; kc1 = kn1;
#pragma unroll
        for (int dt = 0; dt < 4; dt++) vc[dt] = vn[dt];
    }

    // ---- per-wave l reduction across quads (disjoint keys) ----
#pragma unroll
    for (int qt = 0; qt < 4; qt++) {
        lsum[qt] += __shfl_xor(lsum[qt], 16);
        lsum[qt] += __shfl_xor(lsum[qt], 32);
    }
    if (quad == 0) {
#pragma unroll
        for (int qt = 0; qt < 4; qt++)
            red[12288 + w * 64 + qt * 16 + lo16] = lsum[qt];
    }

    // ---- write partial O^T for dt != w (static reg indices; runtime only in
    //      the LDS address and the store predicate) ----
#pragma unroll
    for (int dt = 0; dt < 4; dt++) {
        const int sl = dt - (dt > w ? 1 : 0);
#pragma unroll
        for (int qt = 0; qt < 4; qt++)
            if (dt != w)
                *(f32x4*)&red[((w * 3 + sl) * 64 + qt * 16 + lo16) * 16 + quad * 4] = oacc[dt][qt];
    }

    // ---- extract own dim-tile via wave-uniform STATIC ladder (no dynamic
    //      register-array indexing -> no scratch) ----
    f32x4 own[4];
    if (w == 0) {
#pragma unroll
        for (int qt = 0; qt < 4; qt++) own[qt] = oacc[0][qt];
    } else if (w == 1) {
#pragma unroll
        for (int qt = 0; qt < 4; qt++) own[qt] = oacc[1][qt];
    } else if (w == 2) {
#pragma unroll
        for (int qt = 0; qt < 4; qt++) own[qt] = oacc[2][qt];
    } else {
#pragma unroll
        for (int qt = 0; qt < 4; qt++) own[qt] = oacc[3][qt];
    }
    __syncthreads();

    // ---- wave w owns dim-tile w: add the other 3 waves' partials ----
#pragma unroll
    for (int ow = 0; ow < 4; ow++) {
        const int sl = w - (w > ow ? 1 : 0);
#pragma unroll
        for (int qt = 0; qt < 4; qt++)
            if (ow != w)
                own[qt] += *(const f32x4*)&red[((ow * 3 + sl) * 64 + qt * 16 + lo16) * 16 + quad * 4];
    }

    // ---- normalize, pack bf16, store ----
#pragma unroll
    for (int qt = 0; qt < 4; qt++) {
        const int q = qt * 16 + lo16;
        const float lt = red[12288 + q] + red[12288 + 64 + q]
                       + red[12288 + 128 + q] + red[12288 + 192 + q];
        const float inv = 1.0f / lt;
        f32x4 o = own[qt] * inv;
        union { float f; unsigned u; } a0, a1, a2, a3;
        a0.f = o[0]; a1.f = o[1]; a2.f = o[2]; a3.f = o[3];
        uint2 pk;
        pk.x = __builtin_amdgcn_perm(a1.u, a0.u, sel);
        pk.y = __builtin_amdgcn_perm(a3.u, a2.u, sel);
        *(uint2*)(ab + (size_t)(b * SEQ + q0 + q) * NX + h * DHEAD + w * 16 + quad * 4) = pk;
    }
}

// ---------------------------------------------------------------------------
extern "C" void kernel_launch(void* const* d_in, const int* in_sizes, int n_in,
                              void* d_out, int out_size, void* d_ws, size_t ws_size,
                              hipStream_t stream)
{
    const float* hs     = (const float*)d_in[0];
    const float* w_attn = (const float*)d_in[1];
    const float* b_attn = (const float*)d_in[2];
    const float* w_proj = (const float*)d_in[3];
    const float* b_proj = (const float*)d_in[4];
    float* out = (float*)d_out;

    unsigned short* wsu = (unsigned short*)d_ws;
    unsigned short* Abf  = wsu;                      // 4096*768
    unsigned short* WtA  = Abf  + 3145728;           // 2304*768
    unsigned short* WtP  = WtA  + 1769472;           // 768*768
    unsigned short* qbuf = WtP  + 589824;            // [B,H,S,D]
    unsigned short* kbuf = qbuf + 3145728;           // [B,H,S,D]
    unsigned short* vtbf = kbuf + 3145728;           // [B,H,D,S]
    unsigned short* abf  = vtbf + 3145728;           // [B,S,NX] bf16

    // converts
    cvt_k<<<3072, 256, 0, stream>>>(hs, Abf, 786432);
    cvtT_k<<<dim3(72, 24), 256, 0, stream>>>(w_attn, WtA, NX, 3 * NX);
    cvtT_k<<<dim3(24, 24), 256, 0, stream>>>(w_proj, WtP, NX, NX);

    // QKV GEMM
    gemm_bf<0><<<dim3(18, 32), 256, 0, stream>>>(
        Abf, WtA, b_attn, nullptr, qbuf, kbuf, vtbf, MTOK, 3 * NX, NX);

    // attention
    attn_bf<<<768, 256, 0, stream>>>(qbuf, kbuf, vtbf, abf);

    // output projection
    gemm_bf<1><<<dim3(6, 32), 256, 0, stream>>>(
        abf, WtP, b_proj, out, nullptr, nullptr, nullptr, MTOK, NX, NX);
}

// Round 10
// 162.693 us; speedup vs baseline: 1.2732x; 1.1992x over previous
//
#include <hip/hip_runtime.h>

#define NHEAD 12
#define DHEAD 64
#define SEQ   2048
#define NB    2
#define NX    768
#define MTOK  (NB * SEQ)   // 4096

typedef __attribute__((ext_vector_type(8))) short short8;
typedef __attribute__((ext_vector_type(4))) short short4v;
typedef __attribute__((ext_vector_type(4))) float f32x4;

__device__ __forceinline__ unsigned short f2bf(float x) {
    union { float f; unsigned u; } v; v.f = x;
    unsigned r = v.u + 0x7fffu + ((v.u >> 16) & 1u);
    return (unsigned short)(r >> 16);
}

#define MFMA32(a, b, c) __builtin_amdgcn_mfma_f32_16x16x32_bf16(a, b, c, 0, 0, 0)
#define MFMA16(a, b, c) __builtin_amdgcn_mfma_f32_16x16x16bf16_1k(a, b, c, 0, 0, 0)

// ---------------------------------------------------------------------------
// Merged converts (one dispatch instead of three; block-uniform branch):
//   blocks [0,3072):     hs fp32 -> Abf bf16 elementwise (float4/ushort4)
//   blocks [3072,4800):  w_attn [768,2304] -> WtA [2304,768] bf16 transpose
//   blocks [4800,5376):  w_proj [768,768]  -> WtP [768,768]  bf16 transpose
// ---------------------------------------------------------------------------
__global__ __launch_bounds__(256)
void cvt_all(const float* __restrict__ hs,
             const float* __restrict__ wa, const float* __restrict__ wp,
             unsigned short* __restrict__ Abf,
             unsigned short* __restrict__ WtA, unsigned short* __restrict__ WtP)
{
    __shared__ float tile[32][33];
    const int bid = blockIdx.x;
    const int t = threadIdx.x;

    if (bid < 3072) {
        int i = bid * 256 + t;
        if (i >= 786432) return;
        float4 v = ((const float4*)hs)[i];
        ushort4 o;
        o.x = f2bf(v.x); o.y = f2bf(v.y); o.z = f2bf(v.z); o.w = f2bf(v.w);
        ((ushort4*)Abf)[i] = o;
        return;
    }

    const float* W; unsigned short* T; int K, N, bx, by;
    if (bid < 4800) {
        int b2 = bid - 3072;               // 72 x 24
        bx = b2 % 72; by = b2 / 72;
        W = wa; T = WtA; K = NX; N = 3 * NX;
    } else {
        int b2 = bid - 4800;               // 24 x 24
        bx = b2 % 24; by = b2 / 24;
        W = wp; T = WtP; K = NX; N = NX;
    }
    const int r = t >> 5, c = t & 31;
    const int k0 = by * 32, n0 = bx * 32;
#pragma unroll
    for (int i = 0; i < 4; i++)
        tile[r + i * 8][c] = W[(size_t)(k0 + r + i * 8) * N + n0 + c];
    __syncthreads();
#pragma unroll
    for (int i = 0; i < 4; i++) {
        int n = r + i * 8;
        T[(size_t)(n0 + n) * K + k0 + c] = f2bf(tile[c][n]);
    }
}

// ---------------------------------------------------------------------------
// bf16 MFMA GEMM (R5-verified): C[M,N] = A[M,K] @ Bt[N,K]^T + bias.
// MODE 0: QKV epilogue (q,k [B,H,S,D] bf16, q*0.125; v -> [B,H,D,S] bf16).
// MODE 1: fp32 out + bias.
// ---------------------------------------------------------------------------
template<int MODE>
__global__ __launch_bounds__(256, 3)
void gemm_bf(const unsigned short* __restrict__ A,   // [M][K] bf16
             const unsigned short* __restrict__ Bt,  // [N][K] bf16
             const float* __restrict__ bias,
             float* __restrict__ fo,
             unsigned short* __restrict__ qb, unsigned short* __restrict__ kb2,
             unsigned short* __restrict__ vtb,
             int M, int N, int K)
{
    __shared__ __align__(16) unsigned char sm[2][16384];  // [buf][A 8KB | B 8KB]
    const int t = threadIdx.x;
    const int w = t >> 6, lane = t & 63;
    const int lo16 = lane & 15, quad = lane >> 4;
    const int ib = blockIdx.y * 128, jb = blockIdx.x * 128;

    f32x4 acc[4][4];
#pragma unroll
    for (int mt = 0; mt < 4; mt++)
#pragma unroll
        for (int nt = 0; nt < 4; nt++) acc[mt][nt] = (f32x4){0.f, 0.f, 0.f, 0.f};

    const int srow = lane >> 2;   // 0..15 within seg
    const int sj   = lane & 3;

    auto stage = [&](int buf, int k0) {
#pragma unroll
        for (int i = 0; i < 4; i++) {
            const int u   = i * 4 + w;
            const int p   = u >> 3;
            const int row = (u & 7) * 16 + srow;
            const int sc  = sj ^ (row & 3);
            const unsigned short* g = (p == 0)
                ? (A  + (size_t)(ib + row) * K + k0 + sc * 8)
                : (Bt + (size_t)(jb + row) * K + k0 + sc * 8);
            void* lp = &sm[buf][p * 8192 + (u & 7) * 1024];
            __builtin_amdgcn_global_load_lds(
                (const __attribute__((address_space(1))) unsigned int*)g,
                (__attribute__((address_space(3))) unsigned int*)lp, 16, 0, 0);
        }
    };

    const int mrow = (w >> 1) * 64;
    const int nrow = (w & 1) * 64;

    stage(0, 0);
    const int NIT = K / 32;
    for (int kt = 0; kt < NIT; kt++) {
        const int buf = kt & 1;
        __syncthreads();
        if (kt + 1 < NIT) stage(buf ^ 1, (kt + 1) * 32);

        short8 af[4], bf[4];
#pragma unroll
        for (int mt = 0; mt < 4; mt++) {
            const int row = mrow + mt * 16 + lo16;
            af[mt] = *(const short8*)&sm[buf][row * 64 + ((quad ^ (row & 3)) * 16)];
        }
#pragma unroll
        for (int nt = 0; nt < 4; nt++) {
            const int row = nrow + nt * 16 + lo16;
            bf[nt] = *(const short8*)&sm[buf][8192 + row * 64 + ((quad ^ (row & 3)) * 16)];
        }
#pragma unroll
        for (int mt = 0; mt < 4; mt++)
#pragma unroll
            for (int nt = 0; nt < 4; nt++)
                acc[mt][nt] = MFMA32(af[mt], bf[nt], acc[mt][nt]);
    }

    if constexpr (MODE == 0) {
        const int which = jb / NX;   // 0=q 1=k 2=v, uniform per block
#pragma unroll
        for (int nt = 0; nt < 4; nt++) {
            const int j  = jb + nrow + nt * 16 + lo16;
            const int cc = j - which * NX;
            const int hh = cc >> 6, dd = cc & 63;
            const float bj = bias[j];
#pragma unroll
            for (int mt = 0; mt < 4; mt++) {
                const int m0 = ib + mrow + mt * 16 + quad * 4;
                const int bb = m0 >> 11;
                const int s0 = m0 & 2047;
                const size_t hb = (size_t)(bb * NHEAD + hh);
                if (which == 2) {
                    ushort4 pv;
                    pv.x = f2bf(acc[mt][nt][0] + bj);
                    pv.y = f2bf(acc[mt][nt][1] + bj);
                    pv.z = f2bf(acc[mt][nt][2] + bj);
                    pv.w = f2bf(acc[mt][nt][3] + bj);
                    *(ushort4*)(vtb + (hb * DHEAD + dd) * SEQ + s0) = pv;
                } else {
                    unsigned short* dst = (which == 0) ? qb : kb2;
                    const float sc = (which == 0) ? 0.125f : 1.0f;
#pragma unroll
                    for (int r = 0; r < 4; r++)
                        dst[(hb * SEQ + s0 + r) * DHEAD + dd] =
                            f2bf((acc[mt][nt][r] + bj) * sc);
                }
            }
        }
    } else {
#pragma unroll
        for (int nt = 0; nt < 4; nt++) {
            const int j  = jb + nrow + nt * 16 + lo16;
            const float bj = bias[j];
#pragma unroll
            for (int mt = 0; mt < 4; mt++) {
                const int m0 = ib + mrow + mt * 16 + quad * 4;
#pragma unroll
                for (int r = 0; r < 4; r++)
                    fo[(size_t)(m0 + r) * N + j] = acc[mt][nt][r] + bj;
            }
        }
    }
}

// ---------------------------------------------------------------------------
// bf16 flash attention — R5-verified kernel, restored VERBATIM (51.7 us,
// absmax 2.44e-4). Query-split waves (16 queries/wave, all keys), DMA-staged
// double-buffered K/V, x16 PV whose C-reg -> B-frag key correspondence is
// empirically pinned. No-max softmax (scores bounded), deferred l reduction.
// ---------------------------------------------------------------------------
__global__ __launch_bounds__(256, 3)
void attn_bf(const unsigned short* __restrict__ qb, const unsigned short* __restrict__ kb,
             const unsigned short* __restrict__ vtb, unsigned short* __restrict__ ab)
{
    __shared__ __align__(16) unsigned char sm[2][16384];  // [buf][K 8KB | V 8KB]
    const int t = threadIdx.x;
    const int w = t >> 6, lane = t & 63;
    const int lo16 = lane & 15, quad = lane >> 4;

    // XCD-swizzled decode: same bh stays on one XCD for K/V L2 locality
    const int id = blockIdx.x;            // 768
    const int xcd = id & 7, slot = id >> 3;
    const int bh = xcd * 3 + slot % 3;
    const int q0 = (slot / 3) * 64;
    const int b = bh / NHEAD, h = bh % NHEAD;

    const unsigned short* Qb = qb  + (size_t)bh * SEQ * DHEAD;
    const unsigned short* Kb = kb  + (size_t)bh * SEQ * DHEAD;
    const unsigned short* Vb = vtb + (size_t)bh * DHEAD * SEQ;

    // Q^T B-fragment: query = q0 + w*16 + lo16, dims quad*8..+8 per half
    short8 qf[2];
    {
        const size_t qo = (size_t)(q0 + w * 16 + lo16) * DHEAD + quad * 8;
        qf[0] = *(const short8*)(Qb + qo);
        qf[1] = *(const short8*)(Qb + qo + 32);
    }

    // staging: 16 segs of 1KB (K: u=0..7, V: u=8..15); row pitch 128 B
    // (8 chunks of 16 B); chunk j holds global chunk j ^ (row&7).
    const int srow = lane >> 3;   // 0..7 within seg
    const int sj   = lane & 7;
    auto stage = [&](int buf, int k0) {
#pragma unroll
        for (int i = 0; i < 4; i++) {
            const int u   = i * 4 + w;
            const int p   = u >> 3;
            const int row = (u & 7) * 8 + srow;   // key row (K) / dim row (V)
            const int sc  = sj ^ (row & 7);
            const unsigned short* g = (p == 0)
                ? (Kb + (size_t)(k0 + row) * DHEAD + sc * 8)
                : (Vb + (size_t)row * SEQ + k0 + sc * 8);
            void* lp = &sm[buf][p * 8192 + (u & 7) * 1024];
            __builtin_amdgcn_global_load_lds(
                (const __attribute__((address_space(1))) unsigned int*)g,
                (__attribute__((address_space(3))) unsigned int*)lp, 16, 0, 0);
        }
    };

    f32x4 oacc[4];
#pragma unroll
    for (int dt = 0; dt < 4; dt++) oacc[dt] = (f32x4){0.f, 0.f, 0.f, 0.f};
    float lsum = 0.f;

    stage(0, 0);
    for (int kt = 0; kt < SEQ / 64; kt++) {
        const int buf = kt & 1;
        __syncthreads();
        if (kt + 1 < SEQ / 64) stage(buf ^ 1, (kt + 1) * 64);

        // ---- S^T = K @ Q^T: 4 key-subtiles of 16 ----
        f32x4 s[4];
#pragma unroll
        for (int rt = 0; rt < 4; rt++) {
            const int row = rt * 16 + lo16;
            const int rs = row & 7;
            short8 kf0 = *(const short8*)&sm[buf][row * 128 + ((quad ^ rs) * 16)];
            short8 kf1 = *(const short8*)&sm[buf][row * 128 + (((4 + quad) ^ rs) * 16)];
            f32x4 a = (f32x4){0.f, 0.f, 0.f, 0.f};
            a = MFMA32(kf0, qf[0], a);
            a = MFMA32(kf1, qf[1], a);
            s[rt] = a;
        }

        // ---- exp (no max subtraction; deferred l) + pack P fragments ----
        short4v pf[4];
#pragma unroll
        for (int rt = 0; rt < 4; rt++) {
            float p0 = __expf(s[rt][0]), p1 = __expf(s[rt][1]);
            float p2 = __expf(s[rt][2]), p3 = __expf(s[rt][3]);
            lsum += (p0 + p1) + (p2 + p3);
            short4v pv;
            pv[0] = (short)f2bf(p0); pv[1] = (short)f2bf(p1);
            pv[2] = (short)f2bf(p2); pv[3] = (short)f2bf(p3);
            pf[rt] = pv;
        }

        // ---- O^T += V^T @ P^T (K=16 per subtile, x16 MFMA) ----
#pragma unroll
        for (int dt = 0; dt < 4; dt++) {
            const int row = dt * 16 + lo16;
            const int rs = row & 7;
            f32x4 a = oacc[dt];
#pragma unroll
            for (int rt = 0; rt < 4; rt++) {
                const int ch = (2 * rt + (quad >> 1)) ^ rs;
                short4v vf = *(const short4v*)&sm[buf][8192 + row * 128 + ch * 16 + (quad & 1) * 8];
                a = MFMA16(vf, pf[rt], a);
            }
            oacc[dt] = a;
        }
    }

    // deferred l reduction across quads (each quad covered disjoint keys)
    lsum += __shfl_xor(lsum, 16);
    lsum += __shfl_xor(lsum, 32);
    const float inv = 1.0f / lsum;

    // O^T[dim = dt*16 + quad*4 + r][query = lo16] -> ab bf16 [B,S,NX]
    unsigned short* dst = ab + (size_t)(b * SEQ + q0 + w * 16 + lo16) * NX + h * DHEAD;
#pragma unroll
    for (int dt = 0; dt < 4; dt++) {
        ushort4 pv;
        pv.x = f2bf(oacc[dt][0] * inv);
        pv.y = f2bf(oacc[dt][1] * inv);
        pv.z = f2bf(oacc[dt][2] * inv);
        pv.w = f2bf(oacc[dt][3] * inv);
        *(ushort4*)(dst + dt * 16 + quad * 4) = pv;
    }
}

// ---------------------------------------------------------------------------
extern "C" void kernel_launch(void* const* d_in, const int* in_sizes, int n_in,
                              void* d_out, int out_size, void* d_ws, size_t ws_size,
                              hipStream_t stream)
{
    const float* hs     = (const float*)d_in[0];
    const float* w_attn = (const float*)d_in[1];
    const float* b_attn = (const float*)d_in[2];
    const float* w_proj = (const float*)d_in[3];
    const float* b_proj = (const float*)d_in[4];
    float* out = (float*)d_out;

    unsigned short* wsu = (unsigned short*)d_ws;
    unsigned short* Abf  = wsu;                      // 4096*768
    unsigned short* WtA  = Abf  + 3145728;           // 2304*768
    unsigned short* WtP  = WtA  + 1769472;           // 768*768
    unsigned short* qbuf = WtP  + 589824;            // [B,H,S,D]
    unsigned short* kbuf = qbuf + 3145728;           // [B,H,S,D]
    unsigned short* vtbf = kbuf + 3145728;           // [B,H,D,S]
    unsigned short* abf  = vtbf + 3145728;           // [B,S,NX] bf16

    // merged converts (one dispatch)
    cvt_all<<<5376, 256, 0, stream>>>(hs, w_attn, w_proj, Abf, WtA, WtP);

    // QKV GEMM
    gemm_bf<0><<<dim3(18, 32), 256, 0, stream>>>(
        Abf, WtA, b_attn, nullptr, qbuf, kbuf, vtbf, MTOK, 3 * NX, NX);

    // attention
    attn_bf<<<768, 256, 0, stream>>>(qbuf, kbuf, vtbf, abf);

    // output projection
    gemm_bf<1><<<dim3(6, 32), 256, 0, stream>>>(
        abf, WtP, b_proj, out, nullptr, nullptr, nullptr, MTOK, NX, NX);
}